// Round 8
// baseline (498.075 us; speedup 1.0000x reference)
//
#include <hip/hip_runtime.h>
#include <float.h>

#define NLVL 12
#define NB   16
#define NBLK 256    // fallback: node-hist / node-fill block count (fallback arrays stride NBLK)
#define EBLK 2048   // fallback edge-scatter grid
#define FG   1024   // fused persistent grid (4 blocks/CU x 256 CU); also fused cnt/blk width
#define BARLINES 32

// meta: [96..109) base_f | [128..141) base_b | [160..177) base_o | [224..264) seg totals
// bar (128B lines): [0..32) arrival | 32 master | 33 release | [34..34+FG) per-block flags
// packed entry: id(18b) | fl(4b)<<18 | bl(4b)<<22 | tidx(4b)<<26   (N=200k < 2^18)
//
// COHERENCE DISCIPLINE (validated r3-r7): producer stores crossing an internal
// barrier are agent-scope write-through (sti/stf); consumers may use PLAIN loads
// iff the line's final write precedes its first fetch by any cache ("write-once").
// deg -> rowscan -> rowptr are separate write-once arrays; blk bases are folded
// into P5's cur init (no in-place RMW anywhere across a barrier).

struct Params {
    const int *nt, *ninv, *src, *dst, *fl, *bl, *batch;
    const float *We, *be, *Wf, *bf, *Wb, *bb;
    float *hN, *hB, *tabg, *out;
    int *rowptr, *cursor, *col, *nb_f, *nb_b, *onodes, *bsums, *bsums2, *meta, *plarr, *bar;
    int *deg, *rowscan;
    int *cntf, *cntb, *cnto, *blkf, *blkb, *blko;      // fused: FG-wide; fallback: NBLK-stride
    int N, E, M, outN;
};

__device__ __forceinline__ float rlanef(float x, int l) {
    return __int_as_float(__builtin_amdgcn_readlane(__float_as_int(x), l));
}
__device__ __forceinline__ void sti(int* a, int v) {
    __hip_atomic_store(a, v, __ATOMIC_RELAXED, __HIP_MEMORY_SCOPE_AGENT);
}
__device__ __forceinline__ void stf(float* a, float v) {
    __hip_atomic_store(a, v, __ATOMIC_RELAXED, __HIP_MEMORY_SCOPE_AGENT);
}
__device__ __forceinline__ int ald(int* a) {
    return __hip_atomic_load(a, __ATOMIC_RELAXED, __HIP_MEMORY_SCOPE_AGENT);
}
__device__ __forceinline__ int afa(int* a, int v) {
    return __hip_atomic_fetch_add(a, v, __ATOMIC_RELAXED, __HIP_MEMORY_SCOPE_AGENT);
}

// Hierarchical maintenance-free grid barrier (r4/r6/r7-proven structure).
// r8: 32 arrival lines (was 16) -> halves same-address arrival serialization.
__device__ __forceinline__ void gbar3(int* bar, int t) {
    __syncthreads();                       // vmcnt(0): sti/stf drained to MALL
    if (threadIdx.x == 0) {
        const int line = blockIdx.x & (BARLINES - 1);
        const int per  = FG / BARLINES;    // 32 blocks per line
        int a = afa(&bar[line * 32], 1);
        if (a == per * t - 1) {            // captain: last arrival on this line
            int m = afa(&bar[BARLINES * 32], 1);
            if (m == BARLINES * t - 1) {
                sti(&bar[(BARLINES + 1) * 32], t);
            } else {
                while (ald(&bar[(BARLINES + 1) * 32]) < t) __builtin_amdgcn_s_sleep(1);
            }
            for (int b = line; b < FG; b += BARLINES)
                sti(&bar[(BARLINES + 2 + b) * 32], t);
        } else {
            while (ald(&bar[(BARLINES + 2 + blockIdx.x) * 32]) < t) __builtin_amdgcn_s_sleep(4);
        }
    }
    asm volatile("" ::: "memory");
    __syncthreads();
}

// block-local inclusive scan (256 threads, one int each)
__device__ __forceinline__ int blockScanIncl(int v, int* s, int t) {
    s[t] = v; __syncthreads();
    for (int off = 1; off < 256; off <<= 1) {
        int add = (t >= off) ? s[t - off] : 0; __syncthreads();
        s[t] += add; __syncthreads();
    }
    int r = s[t]; __syncthreads();
    return r;
}

// ---------------- per-level sweep body (champion arithmetic, bit-exact) -------
// Clamps are hang-insurance only: no-op on valid CSR (deg <= ~25 here).
template <int DIR>
__device__ __forceinline__ void sweep_level(const Params& p, int lvl,
                                            const float (&w)[64], float bv,
                                            int lane, int wid, int nw, int q, int fb) {
    const int* nb = DIR ? p.nb_b : p.nb_f;
    const int* rp = p.rowptr + (DIR ? p.N : 0);
    int start = p.meta[(DIR ? 128 : 96) + lvl];
    int cnt   = p.meta[(DIR ? 128 : 96) + lvl + 1] - start;
    float* db = DIR ? p.hB : p.hN;
    const int e2 = 2 * p.E;

    int c0 = (int)((long long)cnt * wid / nw);
    int c1 = (int)((long long)cnt * (wid + 1) / nw);
    for (int i = c0; i < c1; i += 4) {
        int my = i + q;
        int v = 0, rpv = 0, rpe = 0;
        if (my < c1) {
            int e = nb[start + my];
            v = e & 0x3FFFF;
            rpv = rp[v]; rpe = rp[v + 1];
            rpv = (rpv < 0) ? 0 : (rpv > e2 ? e2 : rpv);
            rpe = (rpe < rpv) ? rpv : (rpe > e2 ? e2 : rpe);
            if (rpe > rpv + 4096) rpe = rpv + 4096;
        }
        float4 acc = make_float4(0.f, 0.f, 0.f, 0.f);
        for (int cb = rpv; cb < rpe; cb++) {
            int cu = p.col[cb];
            int u = cu & 0x3FFFF;
            int flu = (cu >> 18) & 15, blu = (cu >> 22) & 15;
            const float* sp;
            if (DIR == 0)
                sp = (flu > 0 && flu < lvl) ? (p.hN + (size_t)u * 64)
                                            : (p.tabg + ((cu >> 26) & 15) * 64);
            else
                sp = (blu > 0 && blu < lvl) ? (p.hB + (size_t)u * 64)
                   : (flu > 0)              ? (p.hN + (size_t)u * 64)
                                            : (p.tabg + ((cu >> 26) & 15) * 64);
            const float4 x = *(const float4*)(sp + fb);
            acc.x += x.x; acc.y += x.y; acc.z += x.z; acc.w += x.w;
        }
        #pragma unroll
        for (int qq = 0; qq < 4; qq++) {
            if (i + qq >= c1) break;                    // wave-uniform
            int vs   = __builtin_amdgcn_readlane(v, 16 * qq);
            int degs = __builtin_amdgcn_readlane(rpe, 16 * qq)
                     - __builtin_amdgcn_readlane(rpv, 16 * qq);
            float o = bv * (float)degs;
            #pragma unroll
            for (int m = 0; m < 16; m++) {
                float ax = rlanef(acc.x, 16 * qq + m);
                float ay = rlanef(acc.y, 16 * qq + m);
                float az = rlanef(acc.z, 16 * qq + m);
                float aw = rlanef(acc.w, 16 * qq + m);
                o = fmaf(ax, w[4 * m + 0], o);
                o = fmaf(ay, w[4 * m + 1], o);
                o = fmaf(az, w[4 * m + 2], o);
                o = fmaf(aw, w[4 * m + 3], o);
            }
            stf(&db[(size_t)vs * 64 + lane], o);        // write-through, agent-visible
        }
    }
}

// ---------------- readout body (shared; clamps no-op on valid meta) -----------
__device__ inline void atomicMaxF(float* addr, float val) {
    int* ai = (int*)addr;
    int old = *ai;
    while (__int_as_float(old) < val) {
        int assumed = old;
        old = atomicCAS(ai, assumed, __float_as_int(val));
        if (old == assumed) break;
    }
}

__device__ __forceinline__ void readout_body(const Params& p, int bid, int tid) {
    int lane = tid & 63;
    int b = bid >> 5;
    int sl = bid & 31;
    int a0 = p.meta[160 + b], a1 = p.meta[161 + b];
    a0 = (a0 < 0) ? 0 : (a0 > p.N ? p.N : a0);
    a1 = (a1 < a0) ? a0 : (a1 > p.N ? p.N : a1);
    int cnt = a1 - a0;
    if (cnt == 0) return;
    int lo = a0 + (int)((long long)cnt * sl / 32);
    int hi = a0 + (int)((long long)cnt * (sl + 1) / 32);
    int wcnt = hi - lo;
    int wave = tid >> 6;
    int wl = lo + (wcnt * wave) / 4;
    int wh = lo + (wcnt * (wave + 1)) / 4;
    if (wh <= wl) return;
    float mx = -FLT_MAX, sm = 0.f;
    for (int k = wl; k < wh; k += 64) {
        int take = wh - k; if (take > 64) take = 64;
        int el = (lane < take) ? p.onodes[k + lane] : 0;
        for (int j = 0; j < take; j++) {
            int e = __shfl(el, j, 64);
            int v = e & 0x3FFFF;
            int flv = (e >> 18) & 15, blv = (e >> 22) & 15;
            const float* sp = (blv > 0) ? (p.hB + (size_t)v * 64)
                            : (flv > 0) ? (p.hN + (size_t)v * 64)
                                        : (p.tabg + ((e >> 26) & 15) * 64);
            float x = sp[lane];
            mx = fmaxf(mx, x);
            sm += x;
        }
    }
    atomicMaxF(&p.out[b * 128 + lane], mx);
    atomicAdd(&p.out[b * 128 + 64 + lane], sm);
}

// ===================== FULLY FUSED persistent kernel ==========================
__global__ __launch_bounds__(256) __attribute__((amdgpu_waves_per_eu(4, 4)))
void k_fused(Params p) {
    const int tid = threadIdx.x, bid = blockIdx.x;
    const int lane = tid & 63;
    int* bar = p.bar;
    int ep = 0;
    __shared__ int s[256];
    __shared__ int hist[40];    // fwd [0..12), bwd [12..24), out [24..40)
    __shared__ int cur[48];

    // ---- P1: edge degrees + node hist/plarr (ALL FG blocks) + out/tabg ------
    if (tid < 40) hist[tid] = 0;
    __syncthreads();
    for (int e = bid * 256 + tid; e < p.E; e += FG * 256) {
        atomicAdd(&p.deg[p.dst[e]], 1);
        atomicAdd(&p.deg[p.N + p.src[e]], 1);
    }
    for (int i = bid * 256 + tid; i < p.outN; i += FG * 256)
        stf(&p.out[i], ((i & 127) < 64) ? -FLT_MAX : 0.0f);
    if (bid == 0 && tid < 64) {
        #pragma unroll
        for (int row = 0; row < 9; row++) {
            float nf = (float)(row / 3), iv = (float)(row % 3);
            stf(&p.tabg[row * 64 + tid],
                fmaf(nf, p.We[tid], fmaf(iv, p.We[64 + tid], p.be[tid])));
        }
    }
    {
        const int chunk = (p.N + FG - 1) / FG;        // same chunk map as P5 node fill!
        int lo = bid * chunk, hi = lo + chunk; if (hi > p.N) hi = p.N;
        for (int i = lo + tid; i < hi; i += 256) {
            int f = p.fl[i], b = p.bl[i];
            int t2 = p.nt[i], iv = p.ninv[i];
            sti(&p.plarr[i], f | (b << 4) | ((t2 * 3 + iv) << 8));
            atomicAdd(&hist[f], 1);
            atomicAdd(&hist[12 + b], 1);
            if (t2 == 1) atomicAdd(&hist[24 + p.batch[i]], 1);
        }
    }
    __syncthreads();
    if (tid < NLVL) { sti(&p.cntf[tid * FG + bid], hist[tid]); sti(&p.cntb[tid * FG + bid], hist[12 + tid]); }
    if (tid < NB) sti(&p.cnto[tid * FG + bid], hist[24 + tid]);
    gbar3(bar, ++ep);

    // ---- P2: deg -> rowscan chunk scans + 40 FG-wide seg scans (4/thread) ----
    const int nscan = (p.M + 511) >> 9;          // 782; 782+2+40 <= FG
    if (bid < nscan) {
        int g0 = (bid << 9) + tid * 2;
        int e0 = (g0 < p.M) ? p.deg[g0] : 0;
        int e1 = (g0 + 1 < p.M) ? p.deg[g0 + 1] : 0;
        int incl = blockScanIncl(e0 + e1, s, tid);
        int excl = incl - (e0 + e1);
        if (g0 < p.M) sti(&p.rowscan[g0], excl);
        if (g0 + 1 < p.M) sti(&p.rowscan[g0 + 1], excl + e0);
        if (tid == 255) sti(&p.bsums[bid], incl);
    } else if (bid >= nscan + 2 && bid < nscan + 2 + 2 * NLVL + NB) {
        int j = bid - (nscan + 2);
        const int* sA; int* dA;
        if (j < NLVL)          { sA = p.cntf + j * FG;              dA = p.blkf + j * FG; }
        else if (j < 2 * NLVL) { sA = p.cntb + (j - NLVL) * FG;     dA = p.blkb + (j - NLVL) * FG; }
        else                   { sA = p.cnto + (j - 2 * NLVL) * FG; dA = p.blko + (j - 2 * NLVL) * FG; }
        int i0 = tid * 4;                        // FG == 4*256 exactly
        int v0 = sA[i0], v1 = sA[i0 + 1], v2 = sA[i0 + 2], v3 = sA[i0 + 3];
        int incl = blockScanIncl(v0 + v1 + v2 + v3, s, tid);
        int b0 = incl - (v0 + v1 + v2 + v3);
        sti(&dA[i0], b0); sti(&dA[i0 + 1], b0 + v0);
        sti(&dA[i0 + 2], b0 + v0 + v1); sti(&dA[i0 + 3], b0 + v0 + v1 + v2);
        if (tid == 255) sti(&p.meta[224 + j], incl);
    }
    gbar3(bar, ++ep);

    // ---- P3: bsums -> bsums2 (write-once) + meta level bases -----------------
    if (bid == 0) {
        int i0 = tid * 4;
        int a0 = (i0     < nscan) ? p.bsums[i0]     : 0;
        int a1 = (i0 + 1 < nscan) ? p.bsums[i0 + 1] : 0;
        int a2 = (i0 + 2 < nscan) ? p.bsums[i0 + 2] : 0;
        int a3 = (i0 + 3 < nscan) ? p.bsums[i0 + 3] : 0;
        int incl = blockScanIncl(a0 + a1 + a2 + a3, s, tid);
        int b0 = incl - (a0 + a1 + a2 + a3);
        if (i0     < nscan) sti(&p.bsums2[i0],     b0);
        if (i0 + 1 < nscan) sti(&p.bsums2[i0 + 1], b0 + a0);
        if (i0 + 2 < nscan) sti(&p.bsums2[i0 + 2], b0 + a0 + a1);
        if (i0 + 3 < nscan) sti(&p.bsums2[i0 + 3], b0 + a0 + a1 + a2);
    } else if (bid == 1 && tid < 3) {
        if (tid == 0) { int a = 0; for (int l = 0; l < NLVL; l++) { sti(&p.meta[96 + l], a);  a += p.meta[224 + l]; }            sti(&p.meta[96 + NLVL], a); }
        if (tid == 1) { int a = 0; for (int l = 0; l < NLVL; l++) { sti(&p.meta[128 + l], a); a += p.meta[224 + NLVL + l]; }     sti(&p.meta[128 + NLVL], a); }
        if (tid == 2) { int a = 0; for (int l = 0; l < NB; l++)   { sti(&p.meta[160 + l], a); a += p.meta[224 + 2 * NLVL + l]; } sti(&p.meta[160 + NB], a); }
    }
    gbar3(bar, ++ep);

    // ---- P4: FINAL rowptr/cursor (first-ever write; write-once) --------------
    for (int g = bid * 256 + tid; g < p.M; g += FG * 256) {
        int r = p.rowscan[g] + p.bsums2[g >> 9];
        sti(&p.rowptr[g], r);
        sti(&p.cursor[g], r);
    }
    if (bid == 0 && tid == 0) sti(&p.rowptr[p.M], 2 * p.E);
    gbar3(bar, ++ep);

    // ---- P5: edge CSR fill + node bucket fill (ALL FG blocks) ----------------
    for (int e = bid * 256 + tid; e < p.E; e += FG * 256) {
        int sN = p.src[e], d = p.dst[e];
        sti(&p.col[atomicAdd(&p.cursor[d], 1)],         sN | (p.plarr[sN] << 18));
        sti(&p.col[atomicAdd(&p.cursor[p.N + sN], 1)],   d | (p.plarr[d]  << 18));
    }
    // meta base folded into cur init (replaces the old blkF arrays + extra pass)
    if (tid < NLVL) { cur[tid] = p.blkf[tid * FG + bid] + p.meta[96 + tid];
                      cur[16 + tid] = p.blkb[tid * FG + bid] + p.meta[128 + tid]; }
    if (tid < NB) cur[32 + tid] = p.blko[tid * FG + bid] + p.meta[160 + tid];
    __syncthreads();
    {
        const int chunk = (p.N + FG - 1) / FG;        // SAME map as P1 hist
        int lo = bid * chunk, hi = lo + chunk; if (hi > p.N) hi = p.N;
        for (int i = lo + tid; i < hi; i += 256) {
            int pl = p.plarr[i];
            int lf = pl & 15, lb = (pl >> 4) & 15, tx = (pl >> 8) & 15;
            int pk = i | (pl << 18);
            sti(&p.nb_f[atomicAdd(&cur[lf], 1)], pk);
            sti(&p.nb_b[atomicAdd(&cur[16 + lb], 1)], pk);
            if (tx >= 3 && tx < 6)
                sti(&p.onodes[atomicAdd(&cur[32 + p.batch[i]], 1)], pk);
        }
    }
    gbar3(bar, ++ep);

    // ---- P6: 22 sweep levels, W loaded once per direction --------------------
    const int wid = (bid * 256 + tid) >> 6;
    const int nw  = (FG * 256) >> 6;
    const int q = lane >> 4, fb = (lane & 15) * 4;
    {
        float w[64];
        #pragma unroll
        for (int k = 0; k < 64; k++) w[k] = p.Wf[k * 64 + lane];
        float bv = p.bf[lane];
        for (int lvl = 1; lvl < NLVL; lvl++) {
            sweep_level<0>(p, lvl, w, bv, lane, wid, nw, q, fb);
            gbar3(bar, ++ep);
        }
    }
    {
        float w[64];
        #pragma unroll
        for (int k = 0; k < 64; k++) w[k] = p.Wb[k * 64 + lane];
        float bv = p.bb[lane];
        for (int lvl = 1; lvl < NLVL; lvl++) {
            sweep_level<1>(p, lvl, w, bv, lane, wid, nw, q, fb);
            gbar3(bar, ++ep);                           // incl. bar before readout
        }
    }

    // ---- P7: readout ---------------------------------------------------------
    if (bid < NB * 32) readout_body(p, bid, tid);
}

// ================= fallback multi-kernel path (round-0 proven) ================
__global__ void k_edge_deg(Params p) {
    int g = blockIdx.x * 256 + threadIdx.x, gs = gridDim.x * 256;
    for (int e = g; e < p.E; e += gs) {
        atomicAdd(&p.rowptr[p.dst[e]], 1);
        atomicAdd(&p.rowptr[p.N + p.src[e]], 1);
    }
}

__global__ void k_deg_hist(Params p) {
    __shared__ int hf[NLVL], hb[NLVL], ho[NB];
    int tid = threadIdx.x, bid = blockIdx.x;
    if (tid < NLVL) { hf[tid] = 0; hb[tid] = 0; }
    if (tid < NB) ho[tid] = 0;
    __syncthreads();
    int chunk = (p.N + gridDim.x - 1) / gridDim.x;
    int lo = bid * chunk, hi = lo + chunk; if (hi > p.N) hi = p.N;
    for (int i = lo + tid; i < hi; i += 256) {
        int f = p.fl[i], b = p.bl[i];
        int t = p.nt[i], iv = p.ninv[i];
        p.plarr[i] = f | (b << 4) | ((t * 3 + iv) << 8);
        atomicAdd(&hf[f], 1);
        atomicAdd(&hb[b], 1);
        if (t == 1) atomicAdd(&ho[p.batch[i]], 1);
    }
    __syncthreads();
    if (tid < NLVL) { p.cntf[tid * NBLK + bid] = hf[tid]; p.cntb[tid * NBLK + bid] = hb[tid]; }
    if (tid < NB) p.cnto[tid * NBLK + bid] = ho[tid];
}

__global__ void k_scan1(int* __restrict__ data, int M, int* __restrict__ bsums) {
    __shared__ int s[512];
    int t = threadIdx.x;
    int g = blockIdx.x * 512 + t;
    int v = (g < M) ? data[g] : 0;
    s[t] = v;
    __syncthreads();
    for (int off = 1; off < 512; off <<= 1) {
        int add = (t >= off) ? s[t - off] : 0;
        __syncthreads();
        s[t] += add;
        __syncthreads();
    }
    if (g < M) data[g] = s[t] - v;
    if (t == 511) bsums[blockIdx.x] = s[511];
}

__global__ void k_scan_top(int* __restrict__ bsums, int nblk, Params p,
                           float* __restrict__ out, int outN) {
    __shared__ int s[1024];
    __shared__ int tot[48];
    int t = threadIdx.x;
    int* meta = p.meta;
    for (int i = t; i < outN; i += 1024)
        out[i] = ((i & 127) < 64) ? -FLT_MAX : 0.0f;
    if (t < 576) {
        int row = t >> 6, j = t & 63;
        float nf = (float)(row / 3), iv = (float)(row % 3);
        p.tabg[t] = fmaf(nf, p.We[j], fmaf(iv, p.We[64 + j], p.be[j]));
    }
    int seg = t >> 8, b = t & 255;
    for (int r = 0; r < 3; r++) {
        int l = 4 * r + seg;
        int v = p.cntf[l * NBLK + b];
        s[t] = v; __syncthreads();
        for (int off = 1; off < NBLK; off <<= 1) {
            int add = (b >= off) ? s[t - off] : 0; __syncthreads();
            s[t] += add; __syncthreads();
        }
        p.blkf[l * NBLK + b] = s[t] - v;
        if (b == NBLK - 1) tot[l] = s[t];
        __syncthreads();
    }
    for (int r = 0; r < 3; r++) {
        int l = 4 * r + seg;
        int v = p.cntb[l * NBLK + b];
        s[t] = v; __syncthreads();
        for (int off = 1; off < NBLK; off <<= 1) {
            int add = (b >= off) ? s[t - off] : 0; __syncthreads();
            s[t] += add; __syncthreads();
        }
        p.blkb[l * NBLK + b] = s[t] - v;
        if (b == NBLK - 1) tot[16 + l] = s[t];
        __syncthreads();
    }
    for (int r = 0; r < 4; r++) {
        int l = 4 * r + seg;
        int v = p.cnto[l * NBLK + b];
        s[t] = v; __syncthreads();
        for (int off = 1; off < NBLK; off <<= 1) {
            int add = (b >= off) ? s[t - off] : 0; __syncthreads();
            s[t] += add; __syncthreads();
        }
        p.blko[l * NBLK + b] = s[t] - v;
        if (b == NBLK - 1) tot[32 + l] = s[t];
        __syncthreads();
    }
    if (t == 0) { int a = 0; for (int l = 0; l < NLVL; l++) { meta[96 + l] = a; a += tot[l]; } meta[96 + NLVL] = a; }
    if (t == 1) { int a = 0; for (int l = 0; l < NLVL; l++) { meta[128 + l] = a; a += tot[16 + l]; } meta[128 + NLVL] = a; }
    if (t == 2) { int a = 0; for (int l = 0; l < NB; l++) { meta[160 + l] = a; a += tot[32 + l]; } meta[160 + NB] = a; }
    __syncthreads();
    for (int i = t; i < NLVL * NBLK; i += 1024) p.blkf[i] += meta[96 + (i >> 8)];
    for (int i = t; i < NLVL * NBLK; i += 1024) p.blkb[i] += meta[128 + (i >> 8)];
    for (int i = t; i < NB * NBLK; i += 1024) p.blko[i] += meta[160 + (i >> 8)];
    int v = (t < nblk) ? bsums[t] : 0;
    s[t] = v;
    __syncthreads();
    for (int off = 1; off < 1024; off <<= 1) {
        int add = (t >= off) ? s[t - off] : 0;
        __syncthreads();
        s[t] += add;
        __syncthreads();
    }
    if (t < nblk) bsums[t] = s[t] - v;
}

__global__ void k_scan_add(int* __restrict__ rowptr, int* __restrict__ cursor, int M, int total,
                           const int* __restrict__ bsums) {
    int g = blockIdx.x * blockDim.x + threadIdx.x;
    if (g >= M) return;
    int r = rowptr[g] + bsums[g >> 9];
    rowptr[g] = r;
    cursor[g] = r;
    if (g == 0) rowptr[M] = total;
}

__global__ void k_edge_fill(Params p) {
    int g = blockIdx.x * 256 + threadIdx.x, gs = gridDim.x * 256;
    int N = p.N;
    for (int e = g; e < p.E; e += gs) {
        int s = p.src[e], d = p.dst[e];
        p.col[atomicAdd(&p.cursor[d], 1)] = s | (p.plarr[s] << 18);
        p.col[atomicAdd(&p.cursor[N + s], 1)] = d | (p.plarr[d] << 18);
    }
}

__global__ void k_fill(Params p) {
    __shared__ int cur[48];
    int tid = threadIdx.x, bid = blockIdx.x;
    int N = p.N;
    if (tid < NLVL) { cur[tid] = p.blkf[tid * NBLK + bid]; cur[16 + tid] = p.blkb[tid * NBLK + bid]; }
    if (tid < NB) cur[32 + tid] = p.blko[tid * NBLK + bid];
    __syncthreads();
    int chunk = (N + gridDim.x - 1) / gridDim.x;
    int lo = bid * chunk, hi = lo + chunk; if (hi > N) hi = N;
    for (int i = lo + tid; i < hi; i += 256) {
        int pl = p.plarr[i];
        int lf = pl & 15, lb = (pl >> 4) & 15, tx = (pl >> 8) & 15;
        int pk = i | (pl << 18);
        p.nb_f[atomicAdd(&cur[lf], 1)] = pk;
        p.nb_b[atomicAdd(&cur[16 + lb], 1)] = pk;
        if (tx >= 3 && tx < 6)
            p.onodes[atomicAdd(&cur[32 + p.batch[i]], 1)] = pk;
    }
}

__global__ __launch_bounds__(256) __attribute__((amdgpu_waves_per_eu(4, 4)))
void k_sweep(Params p, int lvl, int dir) {
    const int tid = threadIdx.x, lane = tid & 63;
    const float* W = dir ? p.Wb : p.Wf;
    float w[64];
    #pragma unroll
    for (int k = 0; k < 64; k++) w[k] = W[k * 64 + lane];
    float bv = (dir ? p.bb : p.bf)[lane];
    const int wid = (blockIdx.x * 256 + tid) >> 6;
    const int nw  = (gridDim.x * 256) >> 6;
    const int q = lane >> 4, fb = (lane & 15) * 4;
    if (dir == 0) sweep_level<0>(p, lvl, w, bv, lane, wid, nw, q, fb);
    else          sweep_level<1>(p, lvl, w, bv, lane, wid, nw, q, fb);
}

__global__ void k_readout(Params p) {
    readout_body(p, blockIdx.x, threadIdx.x);
}

extern "C" void kernel_launch(void* const* d_in, const int* in_sizes, int n_in,
                              void* d_out, int out_size, void* d_ws, size_t ws_size,
                              hipStream_t stream) {
    int N = in_sizes[0];
    int E = in_sizes[2] / 2;
    int M = 2 * N;

    Params p;
    p.nt    = (const int*)d_in[0];
    p.ninv  = (const int*)d_in[1];
    p.src   = (const int*)d_in[2];
    p.dst   = (const int*)d_in[2] + E;
    p.fl    = (const int*)d_in[3];
    p.bl    = (const int*)d_in[4];
    p.batch = (const int*)d_in[5];
    p.We    = (const float*)d_in[6];
    p.be    = (const float*)d_in[7];
    p.Wf    = (const float*)d_in[8];
    p.bf    = (const float*)d_in[9];
    p.Wb    = (const float*)d_in[10];
    p.bb    = (const float*)d_in[11];
    p.out   = (float*)d_out;
    p.N = N; p.E = E; p.M = M; p.outN = out_size;

    char* ws = (char*)d_ws;
    size_t off = 0;
    auto alloc = [&](size_t bytes) -> char* {
        char* q = ws + off;
        off = (off + bytes + 255) & ~(size_t)255;
        return q;
    };
    // rowptr + deg + meta + bar adjacent -> one memset zeroes all
    p.rowptr = (int*)  alloc((size_t)(M + 1) * sizeof(int));
    p.deg    = (int*)  alloc((size_t)M * sizeof(int));
    p.meta   = (int*)  alloc(512 * sizeof(int));
    p.bar    = (int*)  alloc((size_t)(BARLINES + 2 + FG) * 32 * sizeof(int));
    size_t zbytes = (size_t)((char*)(p.bar + (BARLINES + 2 + FG) * 32) - (char*)p.rowptr);
    p.hN     = (float*)alloc((size_t)N * 64 * sizeof(float));
    p.hB     = (float*)alloc((size_t)N * 64 * sizeof(float));
    p.tabg   = (float*)alloc(9 * 64 * sizeof(float));
    p.cursor = (int*)  alloc((size_t)M * sizeof(int));
    p.rowscan= (int*)  alloc((size_t)M * sizeof(int));
    p.col    = (int*)  alloc((size_t)2 * E * sizeof(int));
    p.nb_f   = (int*)  alloc((size_t)N * sizeof(int));
    p.nb_b   = (int*)  alloc((size_t)N * sizeof(int));
    p.onodes = (int*)  alloc((size_t)N * sizeof(int));
    p.plarr  = (int*)  alloc((size_t)N * sizeof(int));
    p.bsums  = (int*)  alloc(1024 * sizeof(int));
    p.bsums2 = (int*)  alloc(1024 * sizeof(int));
    p.cntf   = (int*)  alloc(NLVL * FG * sizeof(int));
    p.cntb   = (int*)  alloc(NLVL * FG * sizeof(int));
    p.cnto   = (int*)  alloc(NB * FG * sizeof(int));
    p.blkf   = (int*)  alloc(NLVL * FG * sizeof(int));
    p.blkb   = (int*)  alloc(NLVL * FG * sizeof(int));
    p.blko   = (int*)  alloc(NB * FG * sizeof(int));

    int nscan = (M + 511) / 512;            // 782 <= 1024

    // fused path requires co-residency of the full FG grid (r4/r6/r7-proven probe)
    static int g_fused = -2;
    if (g_fused == -2) {
        int mb = 0;
        g_fused = 0;
        if (hipOccupancyMaxActiveBlocksPerMultiprocessor(&mb, k_fused, 256, 0) == hipSuccess
                && mb > 0) {
            int dev = 0;
            hipGetDevice(&dev);
            hipDeviceProp_t props;
            if (hipGetDeviceProperties(&props, dev) == hipSuccess &&
                (long)mb * props.multiProcessorCount >= FG)
                g_fused = 1;
        }
    }

    hipMemsetAsync(p.rowptr, 0, zbytes, stream);
    if (g_fused == 1) {
        k_fused<<<FG, 256, 0, stream>>>(p);
    } else {
        k_edge_deg<<<EBLK, 256, 0, stream>>>(p);
        k_deg_hist<<<NBLK, 256, 0, stream>>>(p);
        k_scan1<<<nscan, 512, 0, stream>>>(p.rowptr, M, p.bsums);
        k_scan_top<<<1, 1024, 0, stream>>>(p.bsums, nscan, p, p.out, out_size);
        k_scan_add<<<(M + 255) / 256, 256, 0, stream>>>(p.rowptr, p.cursor, M, 2 * E, p.bsums);
        k_edge_fill<<<EBLK, 256, 0, stream>>>(p);
        k_fill<<<NBLK, 256, 0, stream>>>(p);
        for (int l = 1; l < NLVL; l++)
            k_sweep<<<1024, 256, 0, stream>>>(p, l, 0);
        for (int l = 1; l < NLVL; l++)
            k_sweep<<<1024, 256, 0, stream>>>(p, l, 1);
        k_readout<<<NB * 32, 256, 0, stream>>>(p);
    }
}